// Round 2
// baseline (1726.872 us; speedup 1.0000x reference)
//
#include <hip/hip_runtime.h>

// DBRX attention layer: B=1, T=2048, D_MODEL=6144, NH=48, NKV=8, HD=128,
// rope_base=5e5 full-dim, clamp +-8, causal, f32 in/out, bf16 MFMA compute.

typedef __attribute__((ext_vector_type(8))) short bf16x8;
typedef __attribute__((ext_vector_type(4))) float f32x4;

__device__ inline short f2bf(float f) {
  union { float f; unsigned u; } v; v.f = f;
  unsigned r = v.u + 0x7fffu + ((v.u >> 16) & 1u);  // round-to-nearest-even
  return (short)(r >> 16);
}

// ---------------- f32 -> bf16 convert (8 elems/thread) ----------------
__global__ void cvt_bf16(const float* __restrict__ in, short* __restrict__ out, int n8) {
  int i = blockIdx.x * 256 + threadIdx.x;
  if (i >= n8) return;
  const float4* p = (const float4*)in;
  float4 a = p[2 * i], b = p[2 * i + 1];
  bf16x8 r;
  r[0] = f2bf(a.x); r[1] = f2bf(a.y); r[2] = f2bf(a.z); r[3] = f2bf(a.w);
  r[4] = f2bf(b.x); r[5] = f2bf(b.y); r[6] = f2bf(b.z); r[7] = f2bf(b.w);
  *((bf16x8*)out + i) = r;
}

// ---------------- bf16 GEMM, B^T input (m97 structure) ----------------
__device__ inline void gload_lds16(const short* g, short* l) {
  __builtin_amdgcn_global_load_lds(
      (const __attribute__((address_space(1))) void*)g,
      (__attribute__((address_space(3))) void*)l, 16, 0, 0);
}

__global__ __launch_bounds__(256) void gemm_bt(const short* __restrict__ A,
                                               const short* __restrict__ B,
                                               float* __restrict__ C,
                                               int M, int N, int K) {
  __shared__ short As[128 * 32];
  __shared__ short Bs[128 * 32];
  int tid = threadIdx.x;
  int wave = tid >> 6, lane = tid & 63;
  int lm = lane & 15, quad = lane >> 4;
  int bm = blockIdx.y * 128, bn = blockIdx.x * 128;
  int wm = (wave >> 1) * 64, wn = (wave & 1) * 64;
  f32x4 acc[4][4] = {};
  for (int k0 = 0; k0 < K; k0 += 32) {
#pragma unroll
    for (int i = 0; i < 2; ++i) {
      int c = tid + i * 256;
      gload_lds16(A + (size_t)(bm + (c >> 2)) * K + k0 + (c & 3) * 8,
                  As + (i * 256 + wave * 64) * 8);
    }
#pragma unroll
    for (int i = 0; i < 2; ++i) {
      int c = tid + i * 256;
      gload_lds16(B + (size_t)(bn + (c >> 2)) * K + k0 + (c & 3) * 8,
                  Bs + (i * 256 + wave * 64) * 8);
    }
    __syncthreads();
    bf16x8 a[4], b[4];
#pragma unroll
    for (int r = 0; r < 4; ++r)
      a[r] = *(const bf16x8*)(As + (wm + r * 16 + lm) * 32 + quad * 8);
#pragma unroll
    for (int c = 0; c < 4; ++c)
      b[c] = *(const bf16x8*)(Bs + (wn + c * 16 + lm) * 32 + quad * 8);
#pragma unroll
    for (int r = 0; r < 4; ++r)
#pragma unroll
      for (int c = 0; c < 4; ++c)
        acc[r][c] = __builtin_amdgcn_mfma_f32_16x16x32_bf16(a[r], b[c], acc[r][c], 0, 0, 0);
    __syncthreads();
  }
#pragma unroll
  for (int r = 0; r < 4; ++r)
#pragma unroll
    for (int c = 0; c < 4; ++c)
#pragma unroll
      for (int e = 0; e < 4; ++e)
        C[(size_t)(bm + wm + r * 16 + quad * 4 + e) * N + (bn + wn + c * 16 + lm)] =
            acc[r][c][e];
}

// ---------------- RoPE + clamp + split/cast ----------------
__global__ void rope_split(const float* __restrict__ qkv, short* __restrict__ Qb,
                           short* __restrict__ Kb, short* __restrict__ Vtb) {
  int idx = blockIdx.x * 256 + threadIdx.x;
  int t = idx >> 12;
  int p = idx & 4095;
  int o = p * 2;
  float2 ab = *(const float2*)(qkv + (size_t)t * 8192 + o);
  float a = ab.x, b = ab.y;
  if (o < 7168) {
    int d = o & 127;
    float ang = (float)t * exp2f((float)d * (-18.931568569324174f / 128.0f));
    float s, c;
    sincosf(ang, &s, &c);
    float a2 = a * c - b * s;
    float b2 = a * s + b * c;
    a = a2; b = b2;
  }
  a = fminf(8.0f, fmaxf(-8.0f, a));
  b = fminf(8.0f, fmaxf(-8.0f, b));
  short sa = f2bf(a), sb = f2bf(b);
  if (o < 6144) {
    int h = o >> 7, d = o & 127;
    short* q = Qb + (size_t)(h * 2048 + t) * 128 + d;
    q[0] = sa; q[1] = sb;
  } else if (o < 7168) {
    int oo = o - 6144; int h = oo >> 7, d = oo & 127;
    short* k = Kb + (size_t)(h * 2048 + t) * 128 + d;
    k[0] = sa; k[1] = sb;
  } else {
    int oo = o - 7168; int h = oo >> 7, d = oo & 127;
    Vtb[(size_t)(h * 128 + d) * 2048 + t]     = sa;
    Vtb[(size_t)(h * 128 + d + 1) * 2048 + t] = sb;
  }
}

// ---------------- DPP helpers: 16-lane butterfly reductions (VALU only) ----------------
template <int CTRL>
__device__ inline float dpp_f(float x) {
  union { float f; int i; } v; v.f = x;
  union { int i; float f; } r;
  r.i = __builtin_amdgcn_update_dpp(0, v.i, CTRL, 0xF, 0xF, true);
  return r.f;
}
// reduce across the 16 contiguous lanes of a DPP row, result broadcast to all 16.
// xor1 = quad_perm[1,0,3,2]=0xB1; xor2 = quad_perm[2,3,0,1]=0x4E;
// then row_half_mirror (0x141) combines quad q with q^1; row_mirror (0x140) the halves.
__device__ inline float rowmax16(float x) {
  x = fmaxf(x, dpp_f<0xB1>(x));
  x = fmaxf(x, dpp_f<0x4E>(x));
  x = fmaxf(x, dpp_f<0x141>(x));
  x = fmaxf(x, dpp_f<0x140>(x));
  return x;
}
__device__ inline float rowsum16(float x) {
  x += dpp_f<0xB1>(x);
  x += dpp_f<0x4E>(x);
  x += dpp_f<0x141>(x);
  x += dpp_f<0x140>(x);
  return x;
}

// ---------------- flash attention (causal, GQA) ----------------
// Rewrite: no K/V LDS staging, no __syncthreads in loop. K/V MFMA B-fragments
// loaded directly from global (contiguous 16B/lane; tiles are L1/L2-resident).
// Softmax max via DPP (VALU); sum kept per-lane, reduced once after the loop.
// Only LDS use: wave-private 2.3KB P round-trip (C-layout -> A-layout).
// mtile = 31 - blockIdx.x so the longest (most-KV) blocks dispatch first.
__global__ __launch_bounds__(256, 4) void flash_attn(const short* __restrict__ Q,
                                                     const short* __restrict__ K,
                                                     const short* __restrict__ Vt,
                                                     short* __restrict__ Ob) {
  __shared__ short Ps[4][16 * 72];  // stride 72: write = 32 banks 2-way (free)
  int mtile = 31 - blockIdx.x;      // long blocks first (triangular balance)
  int h = blockIdx.y;
  int hk = h / 6;  // GQA: kv head = h / (48/8)
  int tid = threadIdx.x, wave = tid >> 6, lane = tid & 63;
  int lm = lane & 15, quad = lane >> 4;
  int qrow0 = mtile * 64 + wave * 16;
  const short* Kb = K + (size_t)hk * 2048 * 128;
  const short* Vb = Vt + (size_t)hk * 128 * 2048;
  // Q fragments (A-layout: m=lane&15, k=quad*8+j), registers for whole loop
  bf16x8 qf[4];
#pragma unroll
  for (int kc = 0; kc < 4; ++kc)
    qf[kc] = *(const bf16x8*)(Q + (size_t)(h * 2048 + qrow0 + lm) * 128 + kc * 32 + quad * 8);
  f32x4 o_acc[8] = {};
  float m_run[4] = {-1e30f, -1e30f, -1e30f, -1e30f};
  float l_lane[4] = {0.f, 0.f, 0.f, 0.f};  // per-lane partial sums
  const float sc = 0.08838834764831845f;   // 1/sqrt(128)
  short* pw = &Ps[wave][0];
  for (int kb = 0; kb <= mtile; ++kb) {
    int kv0 = kb * 64;
    // S = Q K^T, B-frags straight from global K[kv][128]
    f32x4 s[4];
#pragma unroll
    for (int ct = 0; ct < 4; ++ct) {
      f32x4 acc = {};
#pragma unroll
      for (int kc = 0; kc < 4; ++kc) {
        bf16x8 bfr = *(const bf16x8*)(Kb + (size_t)(kv0 + ct * 16 + lm) * 128 + kc * 32 + quad * 8);
        acc = __builtin_amdgcn_mfma_f32_16x16x32_bf16(qf[kc], bfr, acc, 0, 0, 0);
      }
      s[ct] = acc;
    }
    // scale + causal mask (row = qrow0+quad*4+e, col = kv0+ct*16+lm)
#pragma unroll
    for (int ct = 0; ct < 4; ++ct) {
      int col = kv0 + ct * 16 + lm;
#pragma unroll
      for (int e = 0; e < 4; ++e) {
        int row = qrow0 + quad * 4 + e;
        float v = s[ct][e] * sc;
        s[ct][e] = (col > row) ? -1e30f : v;
      }
    }
    // online softmax: row max via DPP (row stats uniform across the 16-lane group)
#pragma unroll
    for (int e = 0; e < 4; ++e) {
      float mx = fmaxf(fmaxf(s[0][e], s[1][e]), fmaxf(s[2][e], s[3][e]));
      mx = rowmax16(mx);
      float mn = fmaxf(m_run[e], mx);
      float alpha = __expf(m_run[e] - mn);
      m_run[e] = mn;
      float ls = 0.f;
#pragma unroll
      for (int ct = 0; ct < 4; ++ct) {
        float pv = __expf(s[ct][e] - mn);  // masked -> 0
        s[ct][e] = pv;
        ls += pv;
      }
      l_lane[e] = l_lane[e] * alpha + ls;
#pragma unroll
      for (int ot = 0; ot < 8; ++ot) o_acc[ot][e] *= alpha;
    }
    // P: C-layout regs -> LDS -> A-layout frags (wave-private, no barrier)
#pragma unroll
    for (int ct = 0; ct < 4; ++ct)
#pragma unroll
      for (int e = 0; e < 4; ++e)
        pw[(quad * 4 + e) * 72 + ct * 16 + lm] = f2bf(s[ct][e]);
#pragma unroll
    for (int kc = 0; kc < 2; ++kc) {
      bf16x8 afr = *(const bf16x8*)(pw + lm * 72 + kc * 32 + quad * 8);
#pragma unroll
      for (int ot = 0; ot < 8; ++ot) {
        bf16x8 bfr = *(const bf16x8*)(Vb + (size_t)(ot * 16 + lm) * 2048 + kv0 + kc * 32 + quad * 8);
        o_acc[ot] = __builtin_amdgcn_mfma_f32_16x16x32_bf16(afr, bfr, o_acc[ot], 0, 0, 0);
      }
    }
  }
  // epilogue: reduce l across the 16-lane group once, O /= l, write bf16
  float l_tot[4];
#pragma unroll
  for (int e = 0; e < 4; ++e) l_tot[e] = rowsum16(l_lane[e]);
#pragma unroll
  for (int ot = 0; ot < 8; ++ot)
#pragma unroll
    for (int e = 0; e < 4; ++e) {
      float v = o_acc[ot][e] / l_tot[e];
      Ob[(size_t)(qrow0 + quad * 4 + e) * 6144 + h * 128 + ot * 16 + lm] = f2bf(v);
    }
}

// ---------------- launch ----------------
extern "C" void kernel_launch(void* const* d_in, const int* in_sizes, int n_in,
                              void* d_out, int out_size, void* d_ws, size_t ws_size,
                              hipStream_t stream) {
  const float* x     = (const float*)d_in[0];
  // d_in[1] = causal_mask: analytic, unused
  const float* w_qkv = (const float*)d_in[2];
  const float* w_out = (const float*)d_in[3];
  float* out = (float*)d_out;

  short* xb    = (short*)d_ws;                       // 2048*6144 bf16
  short* wqkvb = xb + (size_t)2048 * 6144;           // 8192*6144 bf16
  short* woutb = wqkvb + (size_t)8192 * 6144;        // 6144*6144 bf16
  float* qkvf  = (float*)(woutb + (size_t)6144 * 6144);  // 2048*8192 f32
  short* Qb    = (short*)(qkvf + (size_t)2048 * 8192);   // 48*2048*128
  short* Kb    = Qb + (size_t)48 * 2048 * 128;           // 8*2048*128
  short* Vtb   = Kb + (size_t)8 * 2048 * 128;            // 8*128*2048 (transposed)
  short* attnb = Vtb + (size_t)8 * 128 * 2048;           // 2048*6144

  cvt_bf16<<<(2048 * 6144 / 8) / 256, 256, 0, stream>>>(x, xb, 2048 * 6144 / 8);
  cvt_bf16<<<(8192 * 6144 / 8) / 256, 256, 0, stream>>>(w_qkv, wqkvb, 8192 * 6144 / 8);
  cvt_bf16<<<(6144 * 6144 / 8) / 256, 256, 0, stream>>>(w_out, woutb, 6144 * 6144 / 8);

  gemm_bt<<<dim3(8192 / 128, 2048 / 128), 256, 0, stream>>>(xb, wqkvb, qkvf, 2048, 8192, 6144);

  rope_split<<<(2048 * 4096) / 256, 256, 0, stream>>>(qkvf, Qb, Kb, Vtb);

  flash_attn<<<dim3(32, 48), 256, 0, stream>>>(Qb, Kb, Vtb, attnb);

  gemm_bt<<<dim3(6144 / 128, 2048 / 128), 256, 0, stream>>>(attnb, woutb, out, 2048, 6144, 6144);
}